// Round 4
// baseline (253.390 us; speedup 1.0000x reference)
//
#include <hip/hip_runtime.h>

// ---------- partner map ----------

__global__ void partner_init_kernel(int* __restrict__ partner, int n) {
    int stride = gridDim.x * blockDim.x;
    for (int i = blockIdx.x * blockDim.x + threadIdx.x; i < n; i += stride)
        partner[i] = -1;
}

__global__ void partner_build_kernel(const int* __restrict__ faces,
                                     int* __restrict__ partner, int n_faces) {
    int stride = gridDim.x * blockDim.x;
    for (int f = blockIdx.x * blockDim.x + threadIdx.x; f < n_faces; f += stride) {
        int a = faces[2 * f];
        int b = faces[2 * f + 1];
        partner[a] = b;
        partner[b] = a;
    }
}

__device__ __forceinline__ float max4(float4 a) {
    return fmaxf(fmaxf(a.x, a.y), fmaxf(a.z, a.w));
}
__device__ __forceinline__ float max8(float4 a, float4 b) {
    return fmaxf(max4(a), max4(b));
}

// Each WAVE processes one chunk of 512 consecutive floats = 64 (row,c) outputs
// = 2 rows.  All loads are perfectly coalesced (each instruction: 64 lanes x
// 16 B contiguous).  Reassembly of per-rc 8-wide maxes happens in-register
// via shuffles.  Partner merge: lanes 0-31 hold row 2k, lanes 32-63 row 2k+1,
// so partner==row^1 (the universal case here) is __shfl_xor(r, 32).
__global__ void fused_pool_kernel(const float* __restrict__ feat,
                                  const int* __restrict__ partner,
                                  float* __restrict__ out, int n_chunks) {
    int lane     = threadIdx.x & 63;
    int wave     = (blockIdx.x * blockDim.x + threadIdx.x) >> 6;
    int n_waves  = (gridDim.x * blockDim.x) >> 6;

    for (int chunk = wave; chunk < n_chunks; chunk += n_waves) {
        const float* base = feat + (size_t)chunk * 512;
        float4 v0 = *reinterpret_cast<const float4*>(base + lane * 4);
        float4 v1 = *reinterpret_cast<const float4*>(base + 256 + lane * 4);

        float m0 = max4(v0);
        float m1 = max4(v1);
        // pair-merge: lanes 2k,2k+1 both get max of floats [8k, 8k+8) of chunk
        float p0 = fmaxf(m0, __shfl_xor(m0, 1, 64));
        float p1 = fmaxf(m1, __shfl_xor(m1, 1, 64));
        // gather: lane l<32 wants p0 from lane 2l; lane l>=32 wants p1 from 2(l-32)
        int l2 = (2 * lane) & 63;
        float a = __shfl(p0, l2, 64);
        float b = __shfl(p1, l2, 64);
        float r = (lane < 32) ? a : b;

        int rc  = chunk * 64 + lane;
        int row = rc >> 5;
        int pr  = partner[row];

        float rp = __shfl_xor(r, 32, 64);  // partner-row same-channel candidate
        if (pr >= 0) {
            if (pr == (row ^ 1)) {
                r = fmaxf(r, rp);
            } else {
                int c = rc & 31;
                const float4* q = reinterpret_cast<const float4*>(
                    feat + ((size_t)pr * 32 + c) * 8);
                r = fmaxf(r, max8(q[0], q[1]));
            }
        }
        out[rc] = r;
    }
}

// ---------- fallback path (no workspace needed) ----------

__global__ void base_max_kernel(const float* __restrict__ feat,
                                float* __restrict__ out, int n) {
    int stride = gridDim.x * blockDim.x;
    for (int i = blockIdx.x * blockDim.x + threadIdx.x; i < n; i += stride) {
        const float4* p = reinterpret_cast<const float4*>(feat + (size_t)i * 8);
        out[i] = max8(p[0], p[1]);
    }
}

__global__ void face_share_kernel(const int* __restrict__ faces,
                                  float* __restrict__ out, int n_faces) {
    int total = n_faces * 8;
    int stride = gridDim.x * blockDim.x;
    for (int t = blockIdx.x * blockDim.x + threadIdx.x; t < total; t += stride) {
        int face = t >> 3;
        int c4   = (t & 7) << 2;
        size_t f1 = (size_t)faces[2 * face];
        size_t f2 = (size_t)faces[2 * face + 1];
        float* p1 = out + f1 * 32 + c4;
        float* p2 = out + f2 * 32 + c4;
        float4 v1 = *reinterpret_cast<const float4*>(p1);
        float4 v2 = *reinterpret_cast<const float4*>(p2);
        float4 s;
        s.x = fmaxf(v1.x, v2.x);
        s.y = fmaxf(v1.y, v2.y);
        s.z = fmaxf(v1.z, v2.z);
        s.w = fmaxf(v1.w, v2.w);
        *reinterpret_cast<float4*>(p1) = s;
        *reinterpret_cast<float4*>(p2) = s;
    }
}

extern "C" void kernel_launch(void* const* d_in, const int* in_sizes, int n_in,
                              void* d_out, int out_size, void* d_ws, size_t ws_size,
                              hipStream_t stream) {
    const float* feat  = (const float*)d_in[0];   // (1e6, 32, 8) f32
    const int*   faces = (const int*)d_in[1];     // (400000, 2) i32
    float* out = (float*)d_out;                   // (1e6, 32) f32

    const int n_elems = out_size;                 // 32,000,000
    const int n_rows  = out_size / 32;            // 1,000,000
    const int n_faces = in_sizes[1] / 2;          // 400,000

    const int block = 256;
    const size_t partner_bytes = (size_t)n_rows * sizeof(int);

    if (ws_size >= partner_bytes && (n_elems & 63) == 0) {
        int* partner = (int*)d_ws;

        int grid_i = min((n_rows + block - 1) / block, 2048);
        partner_init_kernel<<<grid_i, block, 0, stream>>>(partner, n_rows);

        int grid_f = min((n_faces + block - 1) / block, 2048);
        partner_build_kernel<<<grid_f, block, 0, stream>>>(faces, partner, n_faces);

        int n_chunks = n_elems / 64;              // 500,000 chunks (2 rows each)
        int grid_m = min((n_chunks + 3) / 4, 4096);  // 4 waves per block
        fused_pool_kernel<<<grid_m, block, 0, stream>>>(feat, partner, out, n_chunks);
    } else {
        int grid_a = min((n_elems + block - 1) / block, 4096);
        base_max_kernel<<<grid_a, block, 0, stream>>>(feat, out, n_elems);

        int grid_b = min((n_faces * 8 + block - 1) / block, 4096);
        face_share_kernel<<<grid_b, block, 0, stream>>>(faces, out, n_faces);
    }
}